// Round 17
// baseline (182.453 us; speedup 1.0000x reference)
//
#include <hip/hip_runtime.h>
#include <hip/hip_fp16.h>

// Problem constants: B=16, N=128, H=128, BD=64, P=256
using f16x4 = __attribute__((ext_vector_type(4))) _Float16;
using f16x8 = __attribute__((ext_vector_type(8))) _Float16;
using f32x4 = __attribute__((ext_vector_type(4))) float;
using f32x16 = __attribute__((ext_vector_type(16))) float;

__device__ __forceinline__ f16x4 ld_f16x4(const void* p) {
    return *reinterpret_cast<const f16x4*>(p);
}
__device__ __forceinline__ f16x8 ld_f16x8(const void* p) {
    return *reinterpret_cast<const f16x8*>(p);
}

// ---------------------------------------------------------------------------
// 32x32x16 MFMA layout conventions (gfx950):
//  A[m][k]: m = lane&31, k-slot = (hi = lane>>5, e 0..7)
//  B[k][n]: n = lane&31, k-slot = (hi, e)
//  C/D    : col = lane&31, row = (reg&3) + 8*(reg>>2) + 4*hi   [m74/m101]
// k-slot physical labels are free as long as A and B agree (slot-consistent).
//
//  GEMM1 (transposed, M=p tile of 32, N=j 32): physical k = s*16 + hi*8 + e.
//   D gives p-local row = (r&3)+8*(r>>2)+4hi, j = lane&31.  Regs 0..7 are
//   exactly the K=16 A-frag for GEMM2 kstep 2t under
//   sigma(hi,e) = (e&3)+8*(e>>2)+4*hi; regs 8..15 -> kstep 2t+1.
//  GEMM2: A = u (M=j), B = W3s with slot sigma + bank swizzle.
//
// Prep kernel A: W2bt[p][k] = W2[128+k][p] (f16 plain transpose, 64/row).
//  W3s[kk][row p'][slot 0..1][e 0..7] = W3[k][row], k = kk*16 + (e&3) +
//    8*(e>>2) + 4*h, h = slot ^ ((row>>2)&1)  (bank swizzle folded in).
//  T1h [n][64] = pos[n]@W1; T1bh[n][64] = pos[n]@W1 + b1  (f16 tables).
// ---------------------------------------------------------------------------
__global__ void sp_wconv(const float* __restrict__ W2, const float* __restrict__ W3,
                         const float* __restrict__ pos, const float* __restrict__ W1,
                         const float* __restrict__ b1,
                         _Float16* __restrict__ W2bt, _Float16* __restrict__ W3s,
                         _Float16* __restrict__ T1h, _Float16* __restrict__ T1bh) {
    int t = blockIdx.x * 256 + threadIdx.x;   // grid covers 65536
    if (t < 16384) {
        int p = t >> 6, k = t & 63;
        W2bt[t] = (_Float16)W2[(128 + k) * 256 + p];
    }
    {
        // W3s: 16 kk x 256 rows x 16 f16 = 65536 elements
        int kk = t >> 12, rem = t & 4095;
        int row = rem >> 4, inner = rem & 15;
        int slot = inner >> 3, e = inner & 7;
        int h = slot ^ ((row >> 2) & 1);
        int k = kk * 16 + (e & 3) + 8 * (e >> 2) + 4 * h;
        W3s[t] = (_Float16)W3[k * 256 + row];
    }
#pragma unroll
    for (int h = 0; h < 2; ++h) {
        int idx = t + h * 65536;              // 131072 = 2048 rows x 64
        int row = idx >> 6, k = idx & 63;
        float v = pos[row * 2] * W1[k] + pos[row * 2 + 1] * W1[64 + k];
        T1h[idx]  = (_Float16)v;
        T1bh[idx] = (_Float16)(v + b1[k]);
    }
}

// ---------------------------------------------------------------------------
// Prep kernel B: hp16[b*128+j][p] = hid[b,j,:] @ W2[0:128,p] + b2[p]  (f16)
// ---------------------------------------------------------------------------
__global__ void sp_hpart(const float* __restrict__ hs, const float* __restrict__ W2,
                         const float* __restrict__ b2, _Float16* __restrict__ hp16) {
    __shared__ float sh[8 * 128];
    int rb = blockIdx.x * 8;
    int tid = threadIdx.x;
    for (int t = tid; t < 1024; t += 256) sh[t] = hs[rb * 128 + t];
    __syncthreads();
    float acc[8];
    float bb = b2[tid];
#pragma unroll
    for (int r = 0; r < 8; ++r) acc[r] = bb;
    for (int k = 0; k < 128; ++k) {
        float w = W2[k * 256 + tid];
#pragma unroll
        for (int r = 0; r < 8; ++r) acc[r] += sh[r * 128 + k] * w;
    }
#pragma unroll
    for (int r = 0; r < 8; ++r) hp16[(rb + r) * 256 + tid] = (_Float16)acc[r];
}

// ---------------------------------------------------------------------------
// Main kernel: one block per (b, ph-QUARTER, i-group of 8) -> grid 1024.
// 4 waves; wave wj owns j = wj*32 + (lane&31).
//  r16 structure, occupancy push: eacc[2][2] = 64 AGPR (p'-quarter) + 36KB
//  LDS -> target 3 blocks/CU = 3 waves/SIMD (r16 was latency-bound at 2:
//  per-SIMD issue occupancy ~14%, VMEM L2-latency dominated).
//  GEMM1 duplicated x4 across quarters (+33% total MFMA, floor ~7us — cheap
//  vs the stall). r13's (256,4)/60-VGPR starvation avoided: (256,3) leaves
//  ~106 arch regs.
// LDS: 16kk x 64rows x 32B = 32KB W3 quarter + 4KB pool = 36KB.
// ---------------------------------------------------------------------------
__global__ __launch_bounds__(256, 3) void sp_main(
    const float* __restrict__ b3,
    const _Float16* __restrict__ hp16, const _Float16* __restrict__ W2bt,
    const _Float16* __restrict__ W3s, const _Float16* __restrict__ T1h,
    const _Float16* __restrict__ T1bh, float* __restrict__ pool) {
    __shared__ __align__(16) char sW3[16][2048];   // [kk][64 rows][32B]
    __shared__ _Float16 sPoolH[4][8][64];          // [wj][ii][p'-local]

    const int bid = blockIdx.x;
    const int ig = bid & 15, ph = (bid >> 4) & 3, b = bid >> 6;
    const int tid = threadIdx.x;
    const int wj = tid >> 6, lane = tid & 63;
    const int l31 = lane & 31, hi = lane >> 5;

    // --- stage W3 quarter (32KB): rows [ph*64, ph*64+64) of each kk --------
    {
        const uint4* W3v = (const uint4*)W3s;
        uint4* dst = (uint4*)sW3;
#pragma unroll
        for (int c = 0; c < 8; ++c) {
            int q = c * 256 + tid;             // 0..2047
            int kk = q >> 7, w = q & 127;
            dst[q] = W3v[kk * 512 + ph * 128 + w];
        }
    }

    const int jl = wj * 32 + l31;                       // this lane's j
    const _Float16* tjb = T1bh + (b * 128 + jl) * 64 + hi * 8;
    const _Float16* tib = T1h + (b * 128) * 64 + hi * 8;   // + i*64 per iter
    const _Float16* hpb = hp16 + (b * 128 + jl) * 256;
    const int slotB = (hi ^ ((l31 >> 2) & 1)) * 16;     // bank-swizzled 16B half

    __syncthreads();   // sW3 ready

    // =================== barrier-free loop: 4 iters x 2 i ==================
#pragma unroll 1
    for (int ii2 = 0; ii2 < 4; ++ii2) {
        const int i0 = ig * 8 + ii2 * 2;
        const int i1 = i0 + 1;

        // Opaque passthroughs: block LICM from hoisting i-invariant loads
        // (aw = 64 regs, hp = 32 regs if cached -> r10's spill).
        const _Float16* w2p = W2bt;
        const _Float16* hpp = hpb;
        asm volatile("" : "+v"(w2p), "+v"(hpp));

        // --- benc[iq][s] = relu(T1bh[j] - T1h[i])  k = s*16 + hi*8 + e ------
        f16x8 benc[2][4];
#pragma unroll
        for (int s = 0; s < 4; ++s) {
            f16x8 tbv = ld_f16x8(tjb + s * 16);
            f16x8 cv0 = ld_f16x8(tib + i0 * 64 + s * 16);
            f16x8 cv1 = ld_f16x8(tib + i1 * 64 + s * 16);
#pragma unroll
            for (int e = 0; e < 8; ++e) {
                _Float16 d0 = tbv[e] - cv0[e];
                _Float16 d1 = tbv[e] - cv1[e];
                benc[0][s][e] = d0 > (_Float16)0 ? d0 : (_Float16)0;
                benc[1][s][e] = d1 > (_Float16)0 ? d1 : (_Float16)0;
            }
        }

        f32x16 eacc[2][2];   // [iq][nt] -> 64 AGPR
#pragma unroll
        for (int iq = 0; iq < 2; ++iq)
#pragma unroll
            for (int nt = 0; nt < 2; ++nt)
#pragma unroll
                for (int r = 0; r < 16; ++r) eacc[iq][nt][r] = 0.f;

        // --- per p-tile: GEMM1 (full U) -> u-pack -> GEMM2 (2 nt) ----------
#pragma unroll
        for (int t = 0; t < 8; ++t) {
            f32x16 a0, a1;
#pragma unroll
            for (int r = 0; r < 16; ++r) { a0[r] = 0.f; a1[r] = 0.f; }
#pragma unroll
            for (int s = 0; s < 4; ++s) {
                f16x8 aw = ld_f16x8(w2p + (t * 32 + l31) * 64 + s * 16 + hi * 8);
                a0 = __builtin_amdgcn_mfma_f32_32x32x16_f16(aw, benc[0][s], a0, 0, 0, 0);
                a1 = __builtin_amdgcn_mfma_f32_32x32x16_f16(aw, benc[1][s], a1, 0, 0, 0);
            }
            // hp for this lane's j at p = t*32 + {0,8,16,24} + 4hi (+0..3)
            f16x4 hp0 = ld_f16x4(hpp + t * 32 + 4 * hi);
            f16x4 hp1 = ld_f16x4(hpp + t * 32 + 8 + 4 * hi);
            f16x4 hp2 = ld_f16x4(hpp + t * 32 + 16 + 4 * hi);
            f16x4 hp3 = ld_f16x4(hpp + t * 32 + 24 + 4 * hi);
            // u-pack: regs 0..7 -> kstep 2t frag; regs 8..15 -> kstep 2t+1
            f16x8 u00, u01, u10, u11;   // u{iq}{kstephalf}
#pragma unroll
            for (int e = 0; e < 4; ++e) {
                _Float16 v;
                v = (_Float16)a0[e]      + hp0[e]; u00[e]     = v > (_Float16)0 ? v : (_Float16)0;
                v = (_Float16)a0[e + 4]  + hp1[e]; u00[e + 4] = v > (_Float16)0 ? v : (_Float16)0;
                v = (_Float16)a0[e + 8]  + hp2[e]; u01[e]     = v > (_Float16)0 ? v : (_Float16)0;
                v = (_Float16)a0[e + 12] + hp3[e]; u01[e + 4] = v > (_Float16)0 ? v : (_Float16)0;
                v = (_Float16)a1[e]      + hp0[e]; u10[e]     = v > (_Float16)0 ? v : (_Float16)0;
                v = (_Float16)a1[e + 4]  + hp1[e]; u10[e + 4] = v > (_Float16)0 ? v : (_Float16)0;
                v = (_Float16)a1[e + 8]  + hp2[e]; u11[e]     = v > (_Float16)0 ? v : (_Float16)0;
                v = (_Float16)a1[e + 12] + hp3[e]; u11[e + 4] = v > (_Float16)0 ? v : (_Float16)0;
            }
#pragma unroll
            for (int nt = 0; nt < 2; ++nt) {
                const char* rowp = (const char*)sW3 + (nt * 32 + l31) * 32 + slotB;
                f16x8 bf0 = ld_f16x8(rowp + (2 * t) * 2048);
                f16x8 bf1 = ld_f16x8(rowp + (2 * t + 1) * 2048);
                eacc[0][nt] = __builtin_amdgcn_mfma_f32_32x32x16_f16(u00, bf0, eacc[0][nt], 0, 0, 0);
                eacc[1][nt] = __builtin_amdgcn_mfma_f32_32x32x16_f16(u10, bf0, eacc[1][nt], 0, 0, 0);
                eacc[0][nt] = __builtin_amdgcn_mfma_f32_32x32x16_f16(u01, bf1, eacc[0][nt], 0, 0, 0);
                eacc[1][nt] = __builtin_amdgcn_mfma_f32_32x32x16_f16(u11, bf1, eacc[1][nt], 0, 0, 0);
            }
        }

        // --- masked max over 32 j -> sPoolH ---------------------------------
        // eacc: row j = wj*32 + (r&3)+8*(r>>2)+4hi, col p' = ph*64+nt*32+l31
#pragma unroll
        for (int iq = 0; iq < 2; ++iq) {
            const int i = iq ? i1 : i0;
#pragma unroll
            for (int nt = 0; nt < 2; ++nt) {
                float m = -INFINITY;
#pragma unroll
                for (int r = 0; r < 16; ++r) {
                    int jrow = wj * 32 + (r & 3) + 8 * (r >> 2) + 4 * hi;
                    float v = eacc[iq][nt][r];
                    if (jrow != i) m = fmaxf(m, v);
                }
                m = fmaxf(m, __shfl_xor(m, 32));   // combine hi halves
                if (lane < 32) sPoolH[wj][ii2 * 2 + iq][nt * 32 + l31] = (_Float16)m;
            }
        }
    }
    __syncthreads();   // all waves' sPoolH complete

    // --- cross-wave max + b3 -> pooled rows (d_out, write-only) ------------
#pragma unroll
    for (int q = 0; q < 2; ++q) {
        int idx = q * 256 + tid;           // 0..511 = 8 ii x 64 p'-local
        int ii = idx >> 6, t = idx & 63;
        float v = fmaxf(fmaxf((float)sPoolH[0][ii][t], (float)sPoolH[1][ii][t]),
                        fmaxf((float)sPoolH[2][ii][t], (float)sPoolH[3][ii][t]));
        int p = ph * 64 + t;
        pool[(b * 128 + ig * 8 + ii) * 256 + p] = v + b3[p];
    }
}

// ---------------------------------------------------------------------------
// Final: io = io @ Wout + bout, IN PLACE on d_out (8 rows per block; rows
// staged to LDS behind a barrier before any write -> in-place safe).
// ---------------------------------------------------------------------------
__global__ void sp_out(const float* __restrict__ Wout, const float* __restrict__ bout,
                       float* __restrict__ io) {
    __shared__ float sp[8 * 256];
    int rb = blockIdx.x * 8;
    int tid = threadIdx.x;
    for (int t = tid; t < 2048; t += 256) sp[t] = io[rb * 256 + t];
    __syncthreads();
    float acc[8];
    float bb = bout[tid];
#pragma unroll
    for (int r = 0; r < 8; ++r) acc[r] = bb;
    for (int k = 0; k < 256; ++k) {
        float w = Wout[k * 256 + tid];
#pragma unroll
        for (int r = 0; r < 8; ++r) acc[r] += sp[r * 256 + k] * w;
    }
#pragma unroll
    for (int r = 0; r < 8; ++r) io[(rb + r) * 256 + tid] = acc[r];
}

extern "C" void kernel_launch(void* const* d_in, const int* in_sizes, int n_in,
                              void* d_out, int out_size, void* d_ws, size_t ws_size,
                              hipStream_t stream) {
    const float* hs   = (const float*)d_in[0];
    const float* pos  = (const float*)d_in[1];
    const float* W1   = (const float*)d_in[2];
    const float* b1   = (const float*)d_in[3];
    const float* W2   = (const float*)d_in[4];
    const float* b2   = (const float*)d_in[5];
    const float* W3   = (const float*)d_in[6];
    const float* b3   = (const float*)d_in[7];
    const float* Wout = (const float*)d_in[8];
    const float* bout = (const float*)d_in[9];
    float* out = (float*)d_out;

    // ws: hp16 1MB | W2bt 32KB | W3s 128KB | T1h 256KB | T1bh 256KB (~1.7MB)
    _Float16* hp16 = (_Float16*)d_ws;
    _Float16* W2bt = (_Float16*)((char*)d_ws + (1 << 20));
    _Float16* W3s  = (_Float16*)((char*)d_ws + (1 << 20) + 32768);
    _Float16* T1h  = (_Float16*)((char*)d_ws + (1 << 20) + 32768 + 131072);
    _Float16* T1bh = (_Float16*)((char*)d_ws + (1 << 20) + 32768 + 131072 + 262144);

    sp_wconv<<<256, 256, 0, stream>>>(W2, W3, pos, W1, b1, W2bt, W3s, T1h, T1bh);
    sp_hpart<<<256, 256, 0, stream>>>(hs, W2, b2, hp16);
    sp_main<<<1024, 256, 0, stream>>>(b3, hp16, W2bt, W3s, T1h, T1bh, out);
    sp_out<<<256, 256, 0, stream>>>(Wout, bout, out);
}

// Round 18
// 123.129 us; speedup vs baseline: 1.4818x; 1.4818x over previous
//
#include <hip/hip_runtime.h>
#include <hip/hip_fp16.h>

// Problem constants: B=16, N=128, H=128, BD=64, P=256
using f16x4 = __attribute__((ext_vector_type(4))) _Float16;
using f16x8 = __attribute__((ext_vector_type(8))) _Float16;
using f32x4 = __attribute__((ext_vector_type(4))) float;
using f32x16 = __attribute__((ext_vector_type(16))) float;

__device__ __forceinline__ f16x4 ld_f16x4(const void* p) {
    return *reinterpret_cast<const f16x4*>(p);
}
__device__ __forceinline__ f16x8 ld_f16x8(const void* p) {
    return *reinterpret_cast<const f16x8*>(p);
}

// ---------------------------------------------------------------------------
// 32x32x16 MFMA layout conventions (gfx950):
//  A[m][k]: m = lane&31, k-slot = (hi = lane>>5, e 0..7)
//  B[k][n]: n = lane&31, k-slot = (hi, e)
//  C/D    : col = lane&31, row = (reg&3) + 8*(reg>>2) + 4*hi   [m74/m101]
//
//  GEMM1 (transposed, M=p tile of 32, N=j 32): physical k = s*16 + hi*8 + e.
//   D regs 0..7 = K=16 A-frag for GEMM2 kstep 2t under
//   sigma(hi,e) = (e&3)+8*(e>>2)+4*hi; regs 8..15 -> kstep 2t+1.
//  GEMM2: A = u (M=j), B = W3s with slot sigma + bank swizzle.
//
// Prep kernel A: W2bt[p][k] = W2[128+k][p] (f16 plain transpose, 64/row).
//  W3s[kk][row p'][slot 0..1][e 0..7] = W3[k][row], k = kk*16 + (e&3) +
//    8*(e>>2) + 4*h, h = slot ^ ((row>>2)&1)  (bank swizzle folded in).
//  T1h [n][64] = pos[n]@W1; T1bh[n][64] = pos[n]@W1 + b1  (f16 tables).
// ---------------------------------------------------------------------------
__global__ void sp_wconv(const float* __restrict__ W2, const float* __restrict__ W3,
                         const float* __restrict__ pos, const float* __restrict__ W1,
                         const float* __restrict__ b1,
                         _Float16* __restrict__ W2bt, _Float16* __restrict__ W3s,
                         _Float16* __restrict__ T1h, _Float16* __restrict__ T1bh) {
    int t = blockIdx.x * 256 + threadIdx.x;   // grid covers 65536
    if (t < 16384) {
        int p = t >> 6, k = t & 63;
        W2bt[t] = (_Float16)W2[(128 + k) * 256 + p];
    }
    {
        // W3s: 16 kk x 256 rows x 16 f16 = 65536 elements
        int kk = t >> 12, rem = t & 4095;
        int row = rem >> 4, inner = rem & 15;
        int slot = inner >> 3, e = inner & 7;
        int h = slot ^ ((row >> 2) & 1);
        int k = kk * 16 + (e & 3) + 8 * (e >> 2) + 4 * h;
        W3s[t] = (_Float16)W3[k * 256 + row];
    }
#pragma unroll
    for (int h = 0; h < 2; ++h) {
        int idx = t + h * 65536;              // 131072 = 2048 rows x 64
        int row = idx >> 6, k = idx & 63;
        float v = pos[row * 2] * W1[k] + pos[row * 2 + 1] * W1[64 + k];
        T1h[idx]  = (_Float16)v;
        T1bh[idx] = (_Float16)(v + b1[k]);
    }
}

// ---------------------------------------------------------------------------
// Prep kernel B: hp16 in PERMUTED layout: for p = t*32 + q*8 + 4*hi + r,
// store at [(b*128+j)*256 + t*32 + hi*16 + q*4 + r] so sp_main's lane
// (l31, hi) reads its 16 values for tile t as ONE 32B span (2 x f16x8).
// ---------------------------------------------------------------------------
__global__ void sp_hpart(const float* __restrict__ hs, const float* __restrict__ W2,
                         const float* __restrict__ b2, _Float16* __restrict__ hp16) {
    __shared__ float sh[8 * 128];
    int rb = blockIdx.x * 8;
    int tid = threadIdx.x;
    for (int t = tid; t < 1024; t += 256) sh[t] = hs[rb * 128 + t];
    __syncthreads();
    float acc[8];
    float bb = b2[tid];
#pragma unroll
    for (int r = 0; r < 8; ++r) acc[r] = bb;
    for (int k = 0; k < 128; ++k) {
        float w = W2[k * 256 + tid];
#pragma unroll
        for (int r = 0; r < 8; ++r) acc[r] += sh[r * 128 + k] * w;
    }
    // permuted write index for p = tid
    int tt = tid >> 5, rem = tid & 31;
    int q = rem >> 3, hi = (rem >> 2) & 1, rr = tid & 3;
    int widx = tt * 32 + hi * 16 + q * 4 + rr;
#pragma unroll
    for (int r = 0; r < 8; ++r) hp16[(rb + r) * 256 + widx] = (_Float16)acc[r];
}

// ---------------------------------------------------------------------------
// Main kernel: one block per (b, ph-QUARTER, i-group of 8) -> grid 1024,
// __launch_bounds__(256,2) (r13/r17 lesson: never squeeze arch regs).
// 4 waves; wave wj owns j = wj*32 + (lane&31).
//  eacc[2][2] = 64 AGPR -> ~68 regs of scheduler slack at the 2-wave cap
//  (r16 had 8) => the fully-unrolled t-loop can software-pipeline: t+1's
//  aw/hp loads issue under t's MFMAs. GEMM1 x2 vs r16 (+6.5us MFMA floor)
//  is the price; target is the ~58us latency stall.
//  Loads per iter: aw 32, hp 16 (permuted 2xf16x8), cv 8 (tb cached), ds 32.
// LDS: 16kk x 64rows x 32B = 32KB W3 quarter + 4KB pool = 36KB.
// ---------------------------------------------------------------------------
__global__ __launch_bounds__(256, 2) void sp_main(
    const float* __restrict__ b3,
    const _Float16* __restrict__ hp16, const _Float16* __restrict__ W2bt,
    const _Float16* __restrict__ W3s, const _Float16* __restrict__ T1h,
    const _Float16* __restrict__ T1bh, float* __restrict__ pool) {
    __shared__ __align__(16) char sW3[16][2048];   // [kk][64 rows][32B]
    __shared__ _Float16 sPoolH[4][8][64];          // [wj][ii][p'-local]

    const int bid = blockIdx.x;
    const int ig = bid & 15, ph = (bid >> 4) & 3, b = bid >> 6;
    const int tid = threadIdx.x;
    const int wj = tid >> 6, lane = tid & 63;
    const int l31 = lane & 31, hi = lane >> 5;

    // --- stage W3 quarter (32KB): rows [ph*64, ph*64+64) of each kk --------
    {
        const uint4* W3v = (const uint4*)W3s;
        uint4* dst = (uint4*)sW3;
#pragma unroll
        for (int c = 0; c < 8; ++c) {
            int q = c * 256 + tid;             // 0..2047
            int kk = q >> 7, w = q & 127;
            dst[q] = W3v[kk * 512 + ph * 128 + w];
        }
    }

    const int jl = wj * 32 + l31;                       // this lane's j
    const _Float16* tib = T1h + (b * 128) * 64 + hi * 8;   // + i*64 per iter
    const _Float16* hpb = hp16 + (b * 128 + jl) * 256;
    const int slotB = (hi ^ ((l31 >> 2) & 1)) * 16;     // bank-swizzled 16B half

    // --- tb[s] = T1bh[j] fragments (i-invariant, 16 regs, cached) ----------
    f16x8 tb[4];
    {
        const _Float16* tjb = T1bh + (b * 128 + jl) * 64 + hi * 8;
#pragma unroll
        for (int s = 0; s < 4; ++s) tb[s] = ld_f16x8(tjb + s * 16);
    }

    __syncthreads();   // sW3 ready

    // =================== barrier-free loop: 4 iters x 2 i ==================
#pragma unroll 1
    for (int ii2 = 0; ii2 < 4; ++ii2) {
        const int i0 = ig * 8 + ii2 * 2;
        const int i1 = i0 + 1;

        // Opaque passthroughs: block LICM from hoisting i-invariant loads
        // (aw = 64 regs, hp = 32 regs if cached -> r10's spill).
        const _Float16* w2p = W2bt;
        const _Float16* hpp = hpb;
        asm volatile("" : "+v"(w2p), "+v"(hpp));

        // --- benc[iq][s] = relu(tb - T1h[i])  k = s*16 + hi*8 + e -----------
        f16x8 benc[2][4];
#pragma unroll
        for (int s = 0; s < 4; ++s) {
            f16x8 cv0 = ld_f16x8(tib + i0 * 64 + s * 16);
            f16x8 cv1 = ld_f16x8(tib + i1 * 64 + s * 16);
#pragma unroll
            for (int e = 0; e < 8; ++e) {
                _Float16 d0 = tb[s][e] - cv0[e];
                _Float16 d1 = tb[s][e] - cv1[e];
                benc[0][s][e] = d0 > (_Float16)0 ? d0 : (_Float16)0;
                benc[1][s][e] = d1 > (_Float16)0 ? d1 : (_Float16)0;
            }
        }

        f32x16 eacc[2][2];   // [iq][nt] -> 64 AGPR
#pragma unroll
        for (int iq = 0; iq < 2; ++iq)
#pragma unroll
            for (int nt = 0; nt < 2; ++nt)
#pragma unroll
                for (int r = 0; r < 16; ++r) eacc[iq][nt][r] = 0.f;

        // --- per p-tile: GEMM1 -> u-pack -> GEMM2 (2 nt) -------------------
#pragma unroll
        for (int t = 0; t < 8; ++t) {
            f32x16 a0, a1;
#pragma unroll
            for (int r = 0; r < 16; ++r) { a0[r] = 0.f; a1[r] = 0.f; }
#pragma unroll
            for (int s = 0; s < 4; ++s) {
                f16x8 aw = ld_f16x8(w2p + (t * 32 + l31) * 64 + s * 16 + hi * 8);
                a0 = __builtin_amdgcn_mfma_f32_32x32x16_f16(aw, benc[0][s], a0, 0, 0, 0);
                a1 = __builtin_amdgcn_mfma_f32_32x32x16_f16(aw, benc[1][s], a1, 0, 0, 0);
            }
            // hp permuted: lane's 16 values for tile t = one 32B span
            f16x8 hpA = ld_f16x8(hpp + t * 32 + hi * 16);       // q0,q1
            f16x8 hpB = ld_f16x8(hpp + t * 32 + hi * 16 + 8);   // q2,q3
            // u-pack: regs 0..7 -> kstep 2t frag; regs 8..15 -> kstep 2t+1
            f16x8 u00, u01, u10, u11;   // u{iq}{kstephalf}
#pragma unroll
            for (int e = 0; e < 4; ++e) {
                _Float16 v;
                v = (_Float16)a0[e]      + hpA[e];     u00[e]     = v > (_Float16)0 ? v : (_Float16)0;
                v = (_Float16)a0[e + 4]  + hpA[e + 4]; u00[e + 4] = v > (_Float16)0 ? v : (_Float16)0;
                v = (_Float16)a0[e + 8]  + hpB[e];     u01[e]     = v > (_Float16)0 ? v : (_Float16)0;
                v = (_Float16)a0[e + 12] + hpB[e + 4]; u01[e + 4] = v > (_Float16)0 ? v : (_Float16)0;
                v = (_Float16)a1[e]      + hpA[e];     u10[e]     = v > (_Float16)0 ? v : (_Float16)0;
                v = (_Float16)a1[e + 4]  + hpA[e + 4]; u10[e + 4] = v > (_Float16)0 ? v : (_Float16)0;
                v = (_Float16)a1[e + 8]  + hpB[e];     u11[e]     = v > (_Float16)0 ? v : (_Float16)0;
                v = (_Float16)a1[e + 12] + hpB[e + 4]; u11[e + 4] = v > (_Float16)0 ? v : (_Float16)0;
            }
#pragma unroll
            for (int nt = 0; nt < 2; ++nt) {
                const char* rowp = (const char*)sW3 + (nt * 32 + l31) * 32 + slotB;
                f16x8 bf0 = ld_f16x8(rowp + (2 * t) * 2048);
                f16x8 bf1 = ld_f16x8(rowp + (2 * t + 1) * 2048);
                eacc[0][nt] = __builtin_amdgcn_mfma_f32_32x32x16_f16(u00, bf0, eacc[0][nt], 0, 0, 0);
                eacc[1][nt] = __builtin_amdgcn_mfma_f32_32x32x16_f16(u10, bf0, eacc[1][nt], 0, 0, 0);
                eacc[0][nt] = __builtin_amdgcn_mfma_f32_32x32x16_f16(u01, bf1, eacc[0][nt], 0, 0, 0);
                eacc[1][nt] = __builtin_amdgcn_mfma_f32_32x32x16_f16(u11, bf1, eacc[1][nt], 0, 0, 0);
            }
        }

        // --- masked max over 32 j -> sPoolH ---------------------------------
        // eacc: row j = wj*32 + (r&3)+8*(r>>2)+4hi, col p' = ph*64+nt*32+l31
#pragma unroll
        for (int iq = 0; iq < 2; ++iq) {
            const int i = iq ? i1 : i0;
#pragma unroll
            for (int nt = 0; nt < 2; ++nt) {
                float m = -INFINITY;
#pragma unroll
                for (int r = 0; r < 16; ++r) {
                    int jrow = wj * 32 + (r & 3) + 8 * (r >> 2) + 4 * hi;
                    float v = eacc[iq][nt][r];
                    if (jrow != i) m = fmaxf(m, v);
                }
                m = fmaxf(m, __shfl_xor(m, 32));   // combine hi halves
                if (lane < 32) sPoolH[wj][ii2 * 2 + iq][nt * 32 + l31] = (_Float16)m;
            }
        }
    }
    __syncthreads();   // all waves' sPoolH complete

    // --- cross-wave max + b3 -> pooled rows (d_out, write-only) ------------
#pragma unroll
    for (int q = 0; q < 2; ++q) {
        int idx = q * 256 + tid;           // 0..511 = 8 ii x 64 p'-local
        int ii = idx >> 6, t = idx & 63;
        float v = fmaxf(fmaxf((float)sPoolH[0][ii][t], (float)sPoolH[1][ii][t]),
                        fmaxf((float)sPoolH[2][ii][t], (float)sPoolH[3][ii][t]));
        int p = ph * 64 + t;
        pool[(b * 128 + ig * 8 + ii) * 256 + p] = v + b3[p];
    }
}

// ---------------------------------------------------------------------------
// Final: io = io @ Wout + bout, IN PLACE on d_out (8 rows per block; rows
// staged to LDS behind a barrier before any write -> in-place safe).
// ---------------------------------------------------------------------------
__global__ void sp_out(const float* __restrict__ Wout, const float* __restrict__ bout,
                       float* __restrict__ io) {
    __shared__ float sp[8 * 256];
    int rb = blockIdx.x * 8;
    int tid = threadIdx.x;
    for (int t = tid; t < 2048; t += 256) sp[t] = io[rb * 256 + t];
    __syncthreads();
    float acc[8];
    float bb = bout[tid];
#pragma unroll
    for (int r = 0; r < 8; ++r) acc[r] = bb;
    for (int k = 0; k < 256; ++k) {
        float w = Wout[k * 256 + tid];
#pragma unroll
        for (int r = 0; r < 8; ++r) acc[r] += sp[r * 256 + k] * w;
    }
#pragma unroll
    for (int r = 0; r < 8; ++r) io[(rb + r) * 256 + tid] = acc[r];
}

extern "C" void kernel_launch(void* const* d_in, const int* in_sizes, int n_in,
                              void* d_out, int out_size, void* d_ws, size_t ws_size,
                              hipStream_t stream) {
    const float* hs   = (const float*)d_in[0];
    const float* pos  = (const float*)d_in[1];
    const float* W1   = (const float*)d_in[2];
    const float* b1   = (const float*)d_in[3];
    const float* W2   = (const float*)d_in[4];
    const float* b2   = (const float*)d_in[5];
    const float* W3   = (const float*)d_in[6];
    const float* b3   = (const float*)d_in[7];
    const float* Wout = (const float*)d_in[8];
    const float* bout = (const float*)d_in[9];
    float* out = (float*)d_out;

    // ws: hp16 1MB | W2bt 32KB | W3s 128KB | T1h 256KB | T1bh 256KB (~1.7MB)
    _Float16* hp16 = (_Float16*)d_ws;
    _Float16* W2bt = (_Float16*)((char*)d_ws + (1 << 20));
    _Float16* W3s  = (_Float16*)((char*)d_ws + (1 << 20) + 32768);
    _Float16* T1h  = (_Float16*)((char*)d_ws + (1 << 20) + 32768 + 131072);
    _Float16* T1bh = (_Float16*)((char*)d_ws + (1 << 20) + 32768 + 131072 + 262144);

    sp_wconv<<<256, 256, 0, stream>>>(W2, W3, pos, W1, b1, W2bt, W3s, T1h, T1bh);
    sp_hpart<<<256, 256, 0, stream>>>(hs, W2, b2, hp16);
    sp_main<<<1024, 256, 0, stream>>>(b3, hp16, W2bt, W3s, T1h, T1bh, out);
    sp_out<<<256, 256, 0, stream>>>(Wout, bout, out);
}

// Round 20
// 83.535 us; speedup vs baseline: 2.1841x; 1.4740x over previous
//
#include <hip/hip_runtime.h>
#include <hip/hip_fp16.h>

// Problem constants: B=16, N=128, H=128, BD=64, P=256
using f16x4 = __attribute__((ext_vector_type(4))) _Float16;
using f16x8 = __attribute__((ext_vector_type(8))) _Float16;
using f32x4 = __attribute__((ext_vector_type(4))) float;
using f32x16 = __attribute__((ext_vector_type(16))) float;
using u32x4 = __attribute__((ext_vector_type(4))) unsigned int;

__device__ __forceinline__ f16x8 ld_f16x8(const void* p) {
    return *reinterpret_cast<const f16x8*>(p);
}
__device__ __forceinline__ f16x8 ldnt_f16x8(const void* p) {
    return __builtin_nontemporal_load(reinterpret_cast<const f16x8*>(p));
}
__device__ __forceinline__ u32x4 ldnt_u4(const void* p) {
    return __builtin_nontemporal_load(reinterpret_cast<const u32x4*>(p));
}

// ---------------------------------------------------------------------------
// 32x32x16 MFMA layout conventions (gfx950):
//  A[m][k]: m = lane&31, k-slot = (hi = lane>>5, e 0..7)
//  B[k][n]: n = lane&31, k-slot = (hi, e)
//  C/D    : col = lane&31, row = (reg&3) + 8*(reg>>2) + 4*hi   [m74/m101]
//
//  GEMM1 (transposed, M=p tile of 32, N=j 32): physical k = s*16 + hi*8 + e.
//   D regs 0..7 = K=16 A-frag for GEMM2 kstep 2t under
//   sigma(hi,e) = (e&3)+8*(e>>2)+4*hi; regs 8..15 -> kstep 2t+1.
//  GEMM2: A = u (M=j), B = W3s with slot sigma + bank swizzle.
//
// Fused prep kernel (one launch): W2bt, W3s, T1h/T1bh tables, and hp16 in
// PERMUTED layout (for p = tt*32 + q*8 + 4*hi + rr store at
// tt*32 + hi*16 + q*4 + rr) so sp_main reads 16 hp values as one 32B span.
// ---------------------------------------------------------------------------
__global__ void sp_prep(const float* __restrict__ W2, const float* __restrict__ W3,
                        const float* __restrict__ pos, const float* __restrict__ W1,
                        const float* __restrict__ b1, const float* __restrict__ hs,
                        const float* __restrict__ b2,
                        _Float16* __restrict__ W2bt, _Float16* __restrict__ W3s,
                        _Float16* __restrict__ T1h, _Float16* __restrict__ T1bh,
                        _Float16* __restrict__ hp16) {
    __shared__ float sh[8 * 128];
    const int tid = threadIdx.x;
    const int t = blockIdx.x * 256 + tid;   // grid 256 -> covers 65536
    if (t < 16384) {
        int p = t >> 6, k = t & 63;
        W2bt[t] = (_Float16)W2[(128 + k) * 256 + p];
    }
    {
        // W3s: 16 kk x 256 rows x 16 f16 = 65536 elements
        int kk = t >> 12, rem = t & 4095;
        int row = rem >> 4, inner = rem & 15;
        int slot = inner >> 3, e = inner & 7;
        int h = slot ^ ((row >> 2) & 1);
        int k = kk * 16 + (e & 3) + 8 * (e >> 2) + 4 * h;
        W3s[t] = (_Float16)W3[k * 256 + row];
    }
#pragma unroll
    for (int h = 0; h < 2; ++h) {
        int idx = t + h * 65536;              // 131072 = 2048 rows x 64
        int row = idx >> 6, k = idx & 63;
        float v = pos[row * 2] * W1[k] + pos[row * 2 + 1] * W1[64 + k];
        T1h[idx]  = (_Float16)v;
        T1bh[idx] = (_Float16)(v + b1[k]);
    }
    // --- hpart: 8 rows per block, permuted p layout ------------------------
    const int rb = blockIdx.x * 8;
    for (int q = tid; q < 1024; q += 256) sh[q] = hs[rb * 128 + q];
    __syncthreads();
    float acc[8];
    float bb = b2[tid];
#pragma unroll
    for (int r = 0; r < 8; ++r) acc[r] = bb;
    for (int k = 0; k < 128; ++k) {
        float w = W2[k * 256 + tid];
#pragma unroll
        for (int r = 0; r < 8; ++r) acc[r] += sh[r * 128 + k] * w;
    }
    int tt = tid >> 5, rem = tid & 31;
    int q = rem >> 3, hi = (rem >> 2) & 1, rr = tid & 3;
    int widx = tt * 32 + hi * 16 + q * 4 + rr;
#pragma unroll
    for (int r = 0; r < 8; ++r) hp16[(rb + r) * 256 + widx] = (_Float16)acc[r];
}

// ---------------------------------------------------------------------------
// Main kernel: r16 frame (best: 79us sp_main): one block per (b, ph-half,
// i-group of 8) -> grid 512, (256,2), 4 waves, wave wj owns j = wj*32+l31.
// Round-20 changes (attack exposed VMEM latency — r16 was ~90% serial-load
// stall at 2 waves/SIMD):
//  - NONTEMPORAL loads on all streaming reads (hp, cv, tbv, W3 staging):
//    keeps W2bt (32KB, reused x4 iters by all waves) resident in the 32KB
//    L1 -> aw loads drop from L2 (~400cyc) to L1 (~120cyc) latency.
//  - hp one-tile-ahead register prefetch (permuted layout: 2 x f16x8/tile;
//    dbuf = +8 regs, paid for by NOT caching tb) -> hp L2 latency hides
//    under tile t's 24 MFMAs.
// LDS: 64KB W3-half + 8KB pool = 72KB -> 2 blocks/CU.
// ---------------------------------------------------------------------------
__global__ __launch_bounds__(256, 2) void sp_main(
    const float* __restrict__ b3,
    const _Float16* __restrict__ hp16, const _Float16* __restrict__ W2bt,
    const _Float16* __restrict__ W3s, const _Float16* __restrict__ T1h,
    const _Float16* __restrict__ T1bh, float* __restrict__ pool) {
    __shared__ __align__(16) char sW3[16][4096];   // [kk][128 rows][32B]
    __shared__ _Float16 sPoolH[4][8][128];         // [wj][ii][p'-local]

    const int bid = blockIdx.x;
    const int ig = bid & 15, ph = (bid >> 4) & 1, b = bid >> 5;
    const int tid = threadIdx.x;
    const int wj = tid >> 6, lane = tid & 63;
    const int l31 = lane & 31, hi = lane >> 5;

    // --- stage W3 half (64KB), nontemporal (don't pollute L1) --------------
    {
        const u32x4* W3v = (const u32x4*)W3s;
        u32x4* dst = (u32x4*)sW3;
#pragma unroll
        for (int c = 0; c < 16; ++c)
            dst[c * 256 + tid] = ldnt_u4(W3v + c * 512 + ph * 256 + tid);
    }

    const int jl = wj * 32 + l31;                       // this lane's j
    const _Float16* tjb = T1bh + (b * 128 + jl) * 64 + hi * 8;
    const _Float16* tib = T1h + (b * 128) * 64 + hi * 8;   // + i*64 per iter
    const _Float16* hpb = hp16 + (b * 128 + jl) * 256;
    const int slotB = (hi ^ ((l31 >> 2) & 1)) * 16;     // bank-swizzled 16B half

    __syncthreads();   // sW3 ready

    // =================== barrier-free loop: 4 iters x 2 i ==================
#pragma unroll 1
    for (int ii2 = 0; ii2 < 4; ++ii2) {
        const int i0 = ig * 8 + ii2 * 2;
        const int i1 = i0 + 1;

        // Opaque passthroughs: block LICM from hoisting i-invariant loads
        // (aw = 64 regs, hp = 64 regs if cached -> r10's spill).
        const _Float16* w2p = W2bt;
        const _Float16* hpp = hpb;
        asm volatile("" : "+v"(w2p), "+v"(hpp));

        // hp prefetch for tile 0 (latency hides under benc build)
        f16x8 hpA_c = ldnt_f16x8(hpp + hi * 16);
        f16x8 hpB_c = ldnt_f16x8(hpp + hi * 16 + 8);

        // --- benc[iq][s] = relu(T1bh[j] - T1h[i])  k = s*16 + hi*8 + e ------
        f16x8 benc[2][4];
#pragma unroll
        for (int s = 0; s < 4; ++s) {
            f16x8 tbv = ldnt_f16x8(tjb + s * 16);
            f16x8 cv0 = ldnt_f16x8(tib + i0 * 64 + s * 16);
            f16x8 cv1 = ldnt_f16x8(tib + i1 * 64 + s * 16);
#pragma unroll
            for (int e = 0; e < 8; ++e) {
                _Float16 d0 = tbv[e] - cv0[e];
                _Float16 d1 = tbv[e] - cv1[e];
                benc[0][s][e] = d0 > (_Float16)0 ? d0 : (_Float16)0;
                benc[1][s][e] = d1 > (_Float16)0 ? d1 : (_Float16)0;
            }
        }

        f32x16 eacc[2][4];   // [iq][nt] -> 128 AGPR
#pragma unroll
        for (int iq = 0; iq < 2; ++iq)
#pragma unroll
            for (int nt = 0; nt < 4; ++nt)
#pragma unroll
                for (int r = 0; r < 16; ++r) eacc[iq][nt][r] = 0.f;

        // --- per p-tile: GEMM1 (aw L1-hot) -> u-pack (hp prefetched) ->
        //     GEMM2 (4 nt from resident LDS); hp[t+1] issued mid-tile -------
#pragma unroll
        for (int t = 0; t < 8; ++t) {
            f32x16 a0, a1;
#pragma unroll
            for (int r = 0; r < 16; ++r) { a0[r] = 0.f; a1[r] = 0.f; }
#pragma unroll
            for (int s = 0; s < 4; ++s) {
                f16x8 aw = ld_f16x8(w2p + (t * 32 + l31) * 64 + s * 16 + hi * 8);
                a0 = __builtin_amdgcn_mfma_f32_32x32x16_f16(aw, benc[0][s], a0, 0, 0, 0);
                a1 = __builtin_amdgcn_mfma_f32_32x32x16_f16(aw, benc[1][s], a1, 0, 0, 0);
            }
            // issue next tile's hp loads early (hide under u-pack + GEMM2)
            f16x8 hpA_n = hpA_c, hpB_n = hpB_c;
            if (t < 7) {
                hpA_n = ldnt_f16x8(hpp + (t + 1) * 32 + hi * 16);
                hpB_n = ldnt_f16x8(hpp + (t + 1) * 32 + hi * 16 + 8);
            }
            // u-pack: regs 0..7 -> kstep 2t frag; regs 8..15 -> kstep 2t+1
            f16x8 u00, u01, u10, u11;   // u{iq}{kstephalf}
#pragma unroll
            for (int e = 0; e < 4; ++e) {
                _Float16 v;
                v = (_Float16)a0[e]      + hpA_c[e];     u00[e]     = v > (_Float16)0 ? v : (_Float16)0;
                v = (_Float16)a0[e + 4]  + hpA_c[e + 4]; u00[e + 4] = v > (_Float16)0 ? v : (_Float16)0;
                v = (_Float16)a0[e + 8]  + hpB_c[e];     u01[e]     = v > (_Float16)0 ? v : (_Float16)0;
                v = (_Float16)a0[e + 12] + hpB_c[e + 4]; u01[e + 4] = v > (_Float16)0 ? v : (_Float16)0;
                v = (_Float16)a1[e]      + hpA_c[e];     u10[e]     = v > (_Float16)0 ? v : (_Float16)0;
                v = (_Float16)a1[e + 4]  + hpA_c[e + 4]; u10[e + 4] = v > (_Float16)0 ? v : (_Float16)0;
                v = (_Float16)a1[e + 8]  + hpB_c[e];     u11[e]     = v > (_Float16)0 ? v : (_Float16)0;
                v = (_Float16)a1[e + 12] + hpB_c[e + 4]; u11[e + 4] = v > (_Float16)0 ? v : (_Float16)0;
            }
#pragma unroll
            for (int nt = 0; nt < 4; ++nt) {
                const char* rowp = (const char*)sW3 + (nt * 32 + l31) * 32 + slotB;
                f16x8 bf0 = ld_f16x8(rowp + (2 * t) * 4096);
                f16x8 bf1 = ld_f16x8(rowp + (2 * t + 1) * 4096);
                eacc[0][nt] = __builtin_amdgcn_mfma_f32_32x32x16_f16(u00, bf0, eacc[0][nt], 0, 0, 0);
                eacc[1][nt] = __builtin_amdgcn_mfma_f32_32x32x16_f16(u10, bf0, eacc[1][nt], 0, 0, 0);
                eacc[0][nt] = __builtin_amdgcn_mfma_f32_32x32x16_f16(u01, bf1, eacc[0][nt], 0, 0, 0);
                eacc[1][nt] = __builtin_amdgcn_mfma_f32_32x32x16_f16(u11, bf1, eacc[1][nt], 0, 0, 0);
            }
            hpA_c = hpA_n;
            hpB_c = hpB_n;
        }

        // --- masked max over 32 j -> sPoolH ---------------------------------
        // eacc: row j = wj*32 + (r&3)+8*(r>>2)+4hi, col p' = ph*128+nt*32+l31
#pragma unroll
        for (int iq = 0; iq < 2; ++iq) {
            const int i = iq ? i1 : i0;
#pragma unroll
            for (int nt = 0; nt < 4; ++nt) {
                float m = -INFINITY;
#pragma unroll
                for (int r = 0; r < 16; ++r) {
                    int jrow = wj * 32 + (r & 3) + 8 * (r >> 2) + 4 * hi;
                    float v = eacc[iq][nt][r];
                    if (jrow != i) m = fmaxf(m, v);
                }
                m = fmaxf(m, __shfl_xor(m, 32));   // combine hi halves
                if (lane < 32) sPoolH[wj][ii2 * 2 + iq][nt * 32 + l31] = (_Float16)m;
            }
        }
    }
    __syncthreads();   // all waves' sPoolH complete

    // --- cross-wave max + b3 -> pooled rows (d_out, write-only) ------------
#pragma unroll
    for (int q = 0; q < 4; ++q) {
        int idx = q * 256 + tid;           // 0..1023 = 8 ii x 128 p'-local
        int ii = idx >> 7, t = idx & 127;
        float v = fmaxf(fmaxf((float)sPoolH[0][ii][t], (float)sPoolH[1][ii][t]),
                        fmaxf((float)sPoolH[2][ii][t], (float)sPoolH[3][ii][t]));
        int p = ph * 128 + t;
        pool[(b * 128 + ig * 8 + ii) * 256 + p] = v + b3[p];
    }
}

// ---------------------------------------------------------------------------
// Final: io = io @ Wout + bout, IN PLACE on d_out. 4 rows/block (grid 512,
// 2 blocks/CU for latency hiding); rows staged to LDS behind a barrier
// before any write -> in-place safe.
// ---------------------------------------------------------------------------
__global__ void sp_out(const float* __restrict__ Wout, const float* __restrict__ bout,
                       float* __restrict__ io) {
    __shared__ float sp[4 * 256];
    int rb = blockIdx.x * 4;
    int tid = threadIdx.x;
    for (int t = tid; t < 1024; t += 256) sp[t] = io[rb * 256 + t];
    __syncthreads();
    float acc[4];
    float bb = bout[tid];
#pragma unroll
    for (int r = 0; r < 4; ++r) acc[r] = bb;
    for (int k = 0; k < 256; ++k) {
        float w = Wout[k * 256 + tid];
#pragma unroll
        for (int r = 0; r < 4; ++r) acc[r] += sp[r * 256 + k] * w;
    }
#pragma unroll
    for (int r = 0; r < 4; ++r) io[(rb + r) * 256 + tid] = acc[r];
}

extern "C" void kernel_launch(void* const* d_in, const int* in_sizes, int n_in,
                              void* d_out, int out_size, void* d_ws, size_t ws_size,
                              hipStream_t stream) {
    const float* hs   = (const float*)d_in[0];
    const float* pos  = (const float*)d_in[1];
    const float* W1   = (const float*)d_in[2];
    const float* b1   = (const float*)d_in[3];
    const float* W2   = (const float*)d_in[4];
    const float* b2   = (const float*)d_in[5];
    const float* W3   = (const float*)d_in[6];
    const float* b3   = (const float*)d_in[7];
    const float* Wout = (const float*)d_in[8];
    const float* bout = (const float*)d_in[9];
    float* out = (float*)d_out;

    // ws: hp16 1MB | W2bt 32KB | W3s 128KB | T1h 256KB | T1bh 256KB (~1.7MB)
    _Float16* hp16 = (_Float16*)d_ws;
    _Float16* W2bt = (_Float16*)((char*)d_ws + (1 << 20));
    _Float16* W3s  = (_Float16*)((char*)d_ws + (1 << 20) + 32768);
    _Float16* T1h  = (_Float16*)((char*)d_ws + (1 << 20) + 32768 + 131072);
    _Float16* T1bh = (_Float16*)((char*)d_ws + (1 << 20) + 32768 + 131072 + 262144);

    sp_prep<<<256, 256, 0, stream>>>(W2, W3, pos, W1, b1, hs, b2,
                                     W2bt, W3s, T1h, T1bh, hp16);
    sp_main<<<512, 256, 0, stream>>>(b3, hp16, W2bt, W3s, T1h, T1bh, out);
    sp_out<<<512, 256, 0, stream>>>(Wout, bout, out);
}